// Round 2
// baseline (182.783 us; speedup 1.0000x reference)
//
#include <hip/hip_runtime.h>

#define CCH 16
#define DD 64
#define HH 96
#define WW 96
#define HW (HH*WW)
#define DHW (DD*HH*WW)   // 589824
#define CH4 (DHW/4)      // 147456
#define NTH 768          // 16 lh x 48 lc, 2 w-sites per thread
#define DCH 16           // depth outputs per block
#define NBY (DD/DCH)     // 4 depth chunks
#define KTR 1.08f        // 27 * k_harris (S unscaled by 1/27; ranking-invariant)
#define INV27C (1.f/19683.f)

typedef float v2f __attribute__((ext_vector_type(2)));

// DPP row16 shifts: thread layout is lh-fast (lh = tid & 15), so a DPP row of
// 16 lanes == one h-column; bound_ctrl=true zero-fills at row ends (filled
// sites only feed masked-out outputs). Harris is invariant to an up/down swap.
__device__ __forceinline__ float dpp_up(float v) {
    return __int_as_float(__builtin_amdgcn_update_dpp(
        0, __float_as_int(v), 0x111 /*row_shr:1*/, 0xF, 0xF, true));
}
__device__ __forceinline__ float dpp_dn(float v) {
    return __int_as_float(__builtin_amdgcn_update_dpp(
        0, __float_as_int(v), 0x101 /*row_shl:1*/, 0xF, 0xF, true));
}

// R13: issue-count + I$ rewrite.
//  - loadslice is BRANCHLESS per-lane: row-clamped VGPR offsets precomputed
//    once, loads always execute (valid addresses), zeroing via 3 v_pk_mul
//    masks; depth-OOB via one UNIFORM scalar branch. Kills the 3 exec-mask
//    dances per slice the old divergent conditional loads generated.
//  - h-convs written as (up+S)+(S+dn) paired adds so GCNDPPCombine can fold
//    the mov_dpp into v_add_f32_dpp (the old fma form blocked folding).
//  - Sx packs as v_pk_sub (AC-AL, AR-AC); Td uses shared partial sums.
//  - emit is multiply-masked (emv), not branched: wave64 issue time is
//    exec-width independent, the branch only cost SALU.
//  - e<DD compute branch deleted: OOB slices have zeroed inputs -> products 0.
//  - #pragma unroll 3 instead of full unroll: body ~4-5 KB fits L1I (full
//    unroll was ~49 KB of straight-line code > 32 KB I$ -> common-mode fetch
//    stall suspected as the R12 VALUBusy=54% limiter).
__global__ __launch_bounds__(NTH, 6)
void harris_sum_kernel(const float* __restrict__ x, float* __restrict__ pp) {
    __shared__ float red[12];

    const int tid = threadIdx.x;
    const int lh = tid & 15, lc = tid >> 4;   // lc 0..47
    const int c  = blockIdx.z;
    const int H0 = blockIdx.x * 12;
    const int o0 = blockIdx.y * DCH;
    const int gh = H0 + lh - 2;
    const bool rowok = ((unsigned)gh < HH);
    const bool lok = (lc > 0), rok = (lc < 47);
    const float mask  = rowok ? 1.f : 0.f;           // gradient row mask
    const float maskl = (rowok && lok) ? 1.f : 0.f;  // halo site masks (also x-zero masks)
    const float maskr = (rowok && rok) ? 1.f : 0.f;
    const v2f mcv = {mask,  mask};
    const v2f mlv = {maskl, maskl};
    const v2f mrv = {maskr, maskr};
    const float em = (lh >= 2 && lh <= 13) ? 1.f : 0.f;
    const v2f emv = {em, em};

    const int ghc   = min(max(gh, 0), HH - 1);       // row-clamped: always-valid addr
    const int woffc = ghc * WW + (lc << 1);
    const int woffl = lok ? woffc - 2 : woffc;       // w-halo offsets, edge-clamped
    const int woffr = rok ? woffc + 2 : woffc;
    const float* xc = x + (size_t)c * DHW;

    // x window: slices e-1(p), e(m), e+1(n); per slice L/C/R = x[w-2..w+3]
    v2f Lp,Cp,Rp, Lm,Cm,Rm, Ln,Cn,Rn;

    auto loadslice = [&](int e, v2f& L, v2f& C, v2f& R) {
        const int ec = min(max(e, 0), DD - 1);       // depth-clamped (uniform)
        const float* sp = xc + (size_t)(ec * HW);
        C = *(const v2f*)(sp + woffc);
        L = *(const v2f*)(sp + woffl);
        R = *(const v2f*)(sp + woffr);
        if (e != ec) {                               // uniform branch, edge blocks only
            L = (v2f){0.f,0.f}; C = (v2f){0.f,0.f}; R = (v2f){0.f,0.f};
        }
        L *= mlv; C *= mcv; R *= mrv;                // 3 pk muls: row/edge zero-pad
    };

    loadslice(o0 - 2, Lp, Cp, Rp);
    loadslice(o0 - 1, Lm, Cm, Rm);
    loadslice(o0,     Ln, Cn, Rn);

    v2f s2m1[6], s2m2[6];
    #pragma unroll
    for (int f = 0; f < 6; ++f) {
        s2m1[f] = (v2f){0.f,0.f};
        s2m2[f] = (v2f){0.f,0.f};
    }
    v2f hv = {0.f, 0.f};

    #pragma unroll 3
    for (int k = 0; k < DCH + 2; ++k) {       // 18 slices -> 16 output slices
        const int e = o0 - 1 + k;
        v2f Lf = {0.f,0.f}, Cf = {0.f,0.f}, Rf = {0.f,0.f};
        if (k < DCH + 1) loadslice(e + 2, Lf, Cf, Rf);   // prefetch, 1-slice distance

        // depth window (pk)
        const v2f AL = (Lp + Lm) + Ln;
        const v2f AC = (Cp + Cm) + Cn;
        const v2f AR = (Rp + Rm) + Rn;
        const v2f DL = Ln - Lp;
        const v2f DC = Cn - Cp;
        const v2f DR = Rn - Rp;

        // w-convs at sites l,0,1,r
        const v2f SxA = AC - AL;              // (Sxl, Sx0)  pk
        const v2f SxB = AR - AC;              // (Sx1, Sxr)  pk
        const float Txl = fmaf(2.f, AL.y, AL.x + AC.x);
        const float Tx0 = fmaf(2.f, AC.x, AL.y + AC.y);
        const float Tx1 = fmaf(2.f, AC.y, AC.x + AR.x);
        const float Txr = fmaf(2.f, AR.x, AC.y + AR.y);
        const float p01 = DL.y + DC.x, p23 = DC.y + DR.x;
        const float Tdl = DL.x + p01,  Td0 = p01 + DC.y;
        const float Td1 = DC.x + p23,  Tdr = p23 + DR.y;

        // h-convs via DPP; paired-add form -> foldable into v_add_f32_dpp
        #define HX(S)  ((dpp_up(S) + (S)) + (dpp_dn(S) + (S)))
        #define HY(T)  (dpp_dn(T) - dpp_up(T))
        #define HZ(T)  ((dpp_up(T) + (T)) + dpp_dn(T))
        const float glx = HX(SxA.x) * maskl;
        const float gx0 = HX(SxA.y) * mask;
        const float gx1 = HX(SxB.x) * mask;
        const float grx = HX(SxB.y) * maskr;
        const float gly = HY(Txl) * maskl;
        const float gy0 = HY(Tx0) * mask;
        const float gy1 = HY(Tx1) * mask;
        const float gry = HY(Txr) * maskr;
        const float glz = HZ(Tdl) * maskl;
        const float gz0 = HZ(Td0) * mask;
        const float gz1 = HZ(Td1) * mask;
        const float grz = HZ(Tdr) * maskr;
        #undef HX
        #undef HY
        #undef HZ

        // products (own pair packed; halo inlined scalar into FIELD)
        const v2f gxv = {gx0, gx1}, gyv = {gy0, gy1}, gzv = {gz0, gz1};
        const v2f Pxx = gxv*gxv, Pyy = gyv*gyv, Pzz = gzv*gzv;
        const v2f Pxy = gxv*gyv, Pxz = gxv*gzv, Pyz = gyv*gzv;

        // w [1,1,1] on products + h [1,1,1] via fused-DPP adds
        v2f s2c[6];
        #define FIELD(f, Pv, Pl, Pr)                                   \
        {   const float s_ = (Pv).x + (Pv).y;                          \
            const float R0 = (Pl) + s_, R1 = s_ + (Pr);                \
            s2c[f].x = (dpp_up(R0) + R0) + dpp_dn(R0);                 \
            s2c[f].y = (dpp_up(R1) + R1) + dpp_dn(R1); }
        FIELD(0, Pxx, glx*glx, grx*grx)
        FIELD(1, Pyy, gly*gly, gry*gry)
        FIELD(2, Pzz, glz*glz, grz*grz)
        FIELD(3, Pxy, glx*gly, grx*gry)
        FIELD(4, Pxz, glx*glz, grx*grz)
        FIELD(5, Pyz, gly*glz, gry*grz)
        #undef FIELD

        if (k >= 2) {   // emit output slice o = e-1, multiply-masked by emv
            const v2f sxx = (s2m2[0] + s2m1[0]) + s2c[0];
            const v2f syy = (s2m2[1] + s2m1[1]) + s2c[1];
            const v2f szz = (s2m2[2] + s2m1[2]) + s2c[2];
            const v2f sxy = (s2m2[3] + s2m1[3]) + s2c[3];
            const v2f sxz = (s2m2[4] + s2m1[4]) + s2c[4];
            const v2f syz = (s2m2[5] + s2m1[5]) + s2c[5];
            const v2f det = sxx*(syy*szz - syz*syz)
                          - sxy*(sxy*szz - syz*sxz)
                          + sxz*(sxy*syz - syy*sxz);
            const v2f tr = (sxx + syy) + szz;
            hv += (det - KTR*(tr*tr)) * emv;   // unscaled by 27^-3: ranking-invariant
        }
        #pragma unroll
        for (int f = 0; f < 6; ++f) { s2m2[f] = s2m1[f]; s2m1[f] = s2c[f]; }
        Lp = Lm; Cp = Cm; Rp = Rm;
        Lm = Ln; Cm = Cn; Rm = Rn;
        Ln = Lf; Cn = Cf; Rn = Rf;
    }

    float hs = hv.x + hv.y;
    // block reduce -> per-block partial slot (no atomics, no ws init needed)
    #pragma unroll
    for (int o = 32; o > 0; o >>= 1) hs += __shfl_down(hs, o, 64);
    if ((tid & 63) == 0) red[tid >> 6] = hs;
    __syncthreads();
    if (tid == 0) {
        float s = 0.f;
        #pragma unroll
        for (int i = 0; i < 12; ++i) s += red[i];
        pp[c * 32 + blockIdx.y * 8 + blockIdx.x] = s * INV27C;
    }
}

// One-block selection: sum 32 partials/channel (fixed order -> deterministic),
// parallel rank (== serial strict-> scan with index tiebreak), write sidx[8].
__global__ __launch_bounds__(64)
void topk_select_kernel(const float* __restrict__ pp, int* __restrict__ sidx) {
    __shared__ float pv[CCH];
    const int t = threadIdx.x;
    if (t < CCH) {
        float s = 0.f;
        #pragma unroll
        for (int j = 0; j < 32; ++j) s += pp[t * 32 + j];
        pv[t] = s;
    }
    __syncthreads();
    if (t < CCH) {
        const float v = pv[t];
        int r = 0;
        #pragma unroll
        for (int i = 0; i < CCH; ++i) {
            const float u = pv[i];
            r += (u > v) || (u == v && i < t);
        }
        if (r < 8) sidx[r] = t;
    }
}

// Pure streaming copy: 64 B/thread, selection read once per block.
__global__ __launch_bounds__(256)
void gather_kernel(const float* __restrict__ x, const int* __restrict__ sidx,
                   float4* __restrict__ out) {
    const int j = blockIdx.y;                        // 0..7
    const int cidx = sidx[j];                        // uniform
    const float4* src = (const float4*)(x + (size_t)cidx * DHW);
    float4* dst = out + (size_t)j * CH4;
    const int base = blockIdx.x * 1024 + threadIdx.x;   // 144*1024 == CH4 exact
    #pragma unroll
    for (int t = 0; t < 4; ++t)
        dst[base + t * 256] = src[base + t * 256];
}

extern "C" void kernel_launch(void* const* d_in, const int* in_sizes, int n_in,
                              void* d_out, int out_size, void* d_ws, size_t ws_size,
                              hipStream_t stream) {
    const float* x = (const float*)d_in[0];
    float4* out = reinterpret_cast<float4*>(d_out);
    float* pp = (float*)d_ws;                        // 512 per-block partials (2 KB)
    int* sidx = (int*)(pp + 512);                    // +32 B: selected channels

    dim3 g1(8, NBY, CCH);                            // (8,4,16) = 512 blocks
    harris_sum_kernel<<<g1, NTH, 0, stream>>>(x, pp);

    topk_select_kernel<<<1, 64, 0, stream>>>(pp, sidx);

    dim3 g3(CH4 / 1024, 8, 1);                       // (144, 8)
    gather_kernel<<<g3, 256, 0, stream>>>(x, sidx, out);
}